// Round 3
// baseline (403.675 us; speedup 1.0000x reference)
//
#include <hip/hip_runtime.h>
#include <hip/hip_bf16.h>
#include <math.h>

typedef __hip_bfloat16 bf16;
typedef __attribute__((ext_vector_type(8))) short short8;
typedef __attribute__((ext_vector_type(4))) float floatx4;

#define B_ 4
#define L_ 4096
#define D_ 512
#define M_ (B_*L_)   // 16384 rows

__device__ __forceinline__ float b2f(bf16 v){ return __bfloat162float(v); }
__device__ __forceinline__ bf16  f2b(float v){ return __float2bfloat16(v); }
__device__ __forceinline__ short f2bs(float v){ bf16 h = __float2bfloat16(v); short s; __builtin_memcpy(&s,&h,2); return s; }
__device__ __forceinline__ short8 cvt8(float4 a, float4 b){
    short8 s; s[0]=f2bs(a.x); s[1]=f2bs(a.y); s[2]=f2bs(a.z); s[3]=f2bs(a.w);
    s[4]=f2bs(b.x); s[5]=f2bs(b.y); s[6]=f2bs(b.z); s[7]=f2bs(b.w); return s;
}

// ---------------- weight transpose+downcast (K,N) f32 -> (N,K) bf16 ----------------
__global__ __launch_bounds__(1024) void k_transpose(const float* __restrict__ src,
                                                    bf16* __restrict__ dst, int K, int N){
    __shared__ float tile[32][33];
    int n0 = blockIdx.x*32, k0 = blockIdx.y*32;
    int tx = threadIdx.x, ty = threadIdx.y;
    tile[ty][tx] = src[(size_t)(k0+ty)*N + n0+tx];
    __syncthreads();
    ((short*)dst)[(size_t)(n0+ty)*K + k0+tx] = f2bs(tile[tx][ty]);
}

// ---------------- 128x128 MFMA GEMM, K=512, fused epilogues ----------------
// A row-major (M,K); Wt row-major (N,K) bf16. 256 thr = 4 waves 2x2, wave=64x64 (4x4 mfma tiles).
// EPI 0: xproj (bias, split at 512: xbar f32 + xbar bf16 | silu->o3)
// EPI 1: dt    (bias, softplus/clip * A -> la)
// EPI 2: out   (bias -> f32 out)
template<int EPI, bool AF32>
__global__ __launch_bounds__(256) void k_gemm128(const void* __restrict__ Ap,
        const bf16* __restrict__ Wt, const float* __restrict__ bias,
        const float* __restrict__ aux,
        float* __restrict__ o1, bf16* __restrict__ o2, bf16* __restrict__ o3){
    __shared__ short As[128][40];   // +8 pad: 80B row stride -> 2-way bank alias only
    __shared__ short Bs[128][40];
    const int K = 512;
    int m0 = blockIdx.x*128, n0 = blockIdx.y*128;
    int tid=threadIdx.x, w=tid>>6, lane=tid&63;
    int wr=w>>1, wc=w&1, quad=lane>>4, r16=lane&15;
    floatx4 acc[4][4];
    #pragma unroll
    for (int i=0;i<4;i++)
        #pragma unroll
        for (int j=0;j<4;j++)
            #pragma unroll
            for (int e=0;e<4;e++) acc[i][j][e]=0.f;

    int srow = tid>>1, scg = (tid&1)*16;
    for (int k0=0;k0<K;k0+=32){
        if (AF32){
            const float* ap = (const float*)Ap + (size_t)(m0+srow)*K + k0 + scg;
            float4 a0=*(const float4*)ap, a1=*(const float4*)(ap+4),
                   a2=*(const float4*)(ap+8), a3=*(const float4*)(ap+12);
            *(short8*)&As[srow][scg]   = cvt8(a0,a1);
            *(short8*)&As[srow][scg+8] = cvt8(a2,a3);
        } else {
            const short* ap = (const short*)Ap + (size_t)(m0+srow)*K + k0 + scg;
            *(short8*)&As[srow][scg]   = *(const short8*)ap;
            *(short8*)&As[srow][scg+8] = *(const short8*)(ap+8);
        }
        const short* wp = (const short*)Wt + (size_t)(n0+srow)*K + k0 + scg;
        *(short8*)&Bs[srow][scg]   = *(const short8*)wp;
        *(short8*)&Bs[srow][scg+8] = *(const short8*)(wp+8);
        __syncthreads();
        short8 af[4], bv[4];
        #pragma unroll
        for (int i=0;i<4;i++) af[i] = *(short8*)&As[wr*64+i*16+r16][quad*8];
        #pragma unroll
        for (int j=0;j<4;j++) bv[j] = *(short8*)&Bs[wc*64+j*16+r16][quad*8];
        #pragma unroll
        for (int i=0;i<4;i++)
            #pragma unroll
            for (int j=0;j<4;j++)
                acc[i][j] = __builtin_amdgcn_mfma_f32_16x16x32_bf16(af[i], bv[j], acc[i][j], 0,0,0);
        __syncthreads();
    }
    #pragma unroll
    for (int i=0;i<4;i++)
    #pragma unroll
    for (int j=0;j<4;j++)
    #pragma unroll
    for (int reg=0;reg<4;reg++){
        int gr = m0 + wr*64 + i*16 + quad*4 + reg;
        int gc = n0 + wc*64 + j*16 + r16;
        float v = acc[i][j][reg] + bias[gc];
        if (EPI==0){
            if (gc < 512){
                o1[(size_t)gr*512 + gc] = v;
                o2[(size_t)gr*512 + gc] = f2b(v);
            } else {
                o3[(size_t)gr*512 + (gc-512)] = f2b(v / (1.f + expf(-v)));
            }
        } else if (EPI==1){
            float sp = (v > 15.f) ? v : log1pf(expf(v));
            float dt = fminf(fmaxf(sp, 1e-4f), 5.f);
            float Ad = -expf(fminf(fmaxf(aux[gc], -20.f), 2.f));
            o1[(size_t)gr*512 + gc] = fminf(fmaxf(dt*Ad, -18.420680743952367f), 0.f);
        } else {
            o1[(size_t)gr*512 + gc] = v;
        }
    }
}

// ---------------- 64x64 tile core (bf16 A) for the skinny B/C proj ----------------
__device__ __forceinline__ void gemm_tile_64x64(const bf16* __restrict__ Aptr,
                                                const bf16* __restrict__ Wt,
                                                int K, int m0, int n0,
                                                short (*As)[32], short (*Ns)[32],
                                                floatx4 acc[2][2]){
    int tid  = threadIdx.x;
    int w    = tid >> 6, lane = tid & 63;
    int wr   = w >> 1,  wc   = w & 1;
    int quad = lane >> 4, r16 = lane & 15;
    #pragma unroll
    for (int i=0;i<2;i++)
        #pragma unroll
        for (int j=0;j<2;j++)
            #pragma unroll
            for (int e=0;e<4;e++) acc[i][j][e] = 0.f;
    int lrow = tid >> 2, lkg = (tid & 3) * 8;
    for (int k0 = 0; k0 < K; k0 += 32){
        *(short8*)&As[lrow][lkg] = *(const short8*)((const short*)Aptr + (size_t)(m0+lrow)*K + k0 + lkg);
        *(short8*)&Ns[lrow][lkg] = *(const short8*)((const short*)Wt   + (size_t)(n0+lrow)*K + k0 + lkg);
        __syncthreads();
        short8 af[2], bfr[2];
        #pragma unroll
        for (int t=0;t<2;t++) af[t]  = *(short8*)&As[wr*32 + t*16 + r16][quad*8];
        #pragma unroll
        for (int t=0;t<2;t++) bfr[t] = *(short8*)&Ns[wc*32 + t*16 + r16][quad*8];
        #pragma unroll
        for (int i=0;i<2;i++)
            #pragma unroll
            for (int j=0;j<2;j++)
                acc[i][j] = __builtin_amdgcn_mfma_f32_16x16x32_bf16(af[i], bfr[j], acc[i][j], 0,0,0);
        __syncthreads();
    }
}

// ---------------- B/C projection GEMM + rmsnorm over n=64 ----------------
__global__ __launch_bounds__(256) void k_bcproj(const bf16* __restrict__ xbarh,
        const bf16* __restrict__ WtB, const bf16* __restrict__ WtC,
        const float* __restrict__ gB, const float* __restrict__ gC,
        float* __restrict__ Bm, float* __restrict__ Cm){
    __shared__ short As[64][32], Ns[64][32];
    __shared__ float Ls[64][64];
    __shared__ float rfac[64];
    const bf16* Wt = blockIdx.y ? WtC : WtB;
    const float* g = blockIdx.y ? gC  : gB;
    float* outp    = blockIdx.y ? Cm  : Bm;
    floatx4 acc[2][2];
    int m0 = blockIdx.x*64;
    gemm_tile_64x64(xbarh, Wt, 512, m0, 0, As, Ns, acc);
    int tid=threadIdx.x, w=tid>>6, lane=tid&63, wr=w>>1, wc=w&1, quad=lane>>4, r16=lane&15;
    #pragma unroll
    for (int i=0;i<2;i++)
    #pragma unroll
    for (int j=0;j<2;j++)
    #pragma unroll
    for (int reg=0;reg<4;reg++)
        Ls[wr*32+i*16+quad*4+reg][wc*32+j*16+r16] = acc[i][j][reg];
    __syncthreads();
    if (tid < 64){
        float ss = 0.f;
        #pragma unroll
        for (int cc=0;cc<64;cc++){ float t = Ls[tid][cc]; ss += t*t; }
        rfac[tid] = rsqrtf(ss*(1.f/64.f) + 1e-6f);
    }
    __syncthreads();
    #pragma unroll
    for (int it=0; it<16; it++){
        int idx = it*256 + tid;
        int r = idx >> 6, cc = idx & 63;
        outp[(size_t)(m0+r)*64 + cc] = Ls[r][cc] * rfac[r] * g[cc];
    }
}

// ---------------- pass1: fused intra recurrence (zero init) ----------------
// y_zero -> ybuf, final local state -> local, exp(cumsum la) -> dec (in-place over la), atot
__global__ __launch_bounds__(512) void k_pass1(float* __restrict__ la_dec,
        const float* __restrict__ xbar, const float* __restrict__ Bm,
        const float* __restrict__ Cm, float* __restrict__ ybuf,
        float* __restrict__ local, float* __restrict__ atot){
    int c=blockIdx.x, b=blockIdx.y, d=threadIdx.x;
    size_t rowbase=(size_t)b*L_+(size_t)c*64;
    size_t cb=(size_t)c*4+b;
    float4 st[16];
    #pragma unroll
    for (int k=0;k<16;k++) st[k]=make_float4(0.f,0.f,0.f,0.f);
    float cs=0.f, decv=0.f;
    size_t off0 = rowbase*512 + d;
    float la_n = la_dec[off0], x_n = xbar[off0];
    #pragma unroll 2
    for (int i=0;i<64;i++){
        size_t off=(rowbase+i)*512+d;
        float lai=la_n, xi=x_n;
        if (i<63){ la_n=la_dec[off+512]; x_n=xbar[off+512]; }
        float ai=__expf(lai);
        cs += lai;
        decv=__expf(cs);
        la_dec[off]=decv;
        const float* Br=Bm+(rowbase+i)*64;   // wave-uniform rows
        const float* Cr=Cm+(rowbase+i)*64;
        float4 yv=make_float4(0.f,0.f,0.f,0.f);
        #pragma unroll
        for (int k=0;k<16;k++){
            float4 bv=*(const float4*)(Br+k*4);
            float4 cv=*(const float4*)(Cr+k*4);
            float4 s=st[k];
            s.x=fmaf(ai,s.x,bv.x*xi); s.y=fmaf(ai,s.y,bv.y*xi);
            s.z=fmaf(ai,s.z,bv.z*xi); s.w=fmaf(ai,s.w,bv.w*xi);
            st[k]=s;
            yv.x=fmaf(cv.x,s.x,yv.x); yv.y=fmaf(cv.y,s.y,yv.y);
            yv.z=fmaf(cv.z,s.z,yv.z); yv.w=fmaf(cv.w,s.w,yv.w);
        }
        ybuf[off]=(yv.x+yv.y)+(yv.z+yv.w);
    }
    #pragma unroll
    for (int k=0;k<16;k++){
        size_t ob=(cb*64 + k*4)*512 + d;
        local[ob]        = st[k].x;
        local[ob+512]    = st[k].y;
        local[ob+1024]   = st[k].z;
        local[ob+1536]   = st[k].w;
    }
    atot[cb*512+d]=decv;
}

// ---------------- sequential inter-chunk scan (in place) ----------------
__global__ __launch_bounds__(256) void k_scan(float* __restrict__ local,
        const float* __restrict__ atot){
    int idx = blockIdx.x*256 + threadIdx.x;      // over b*n*d = 131072
    int d = idx & 511, n = (idx >> 9) & 63, b = idx >> 15;
    float s = 0.f;
    for (int c=0;c<64;c++){
        size_t cb = (size_t)c*4 + b;
        size_t off = (cb*64 + n)*512 + d;
        float v = local[off];
        local[off] = s;                           // state entering chunk c
        s = s * atot[cb*512 + d] + v;
        if (!isfinite(s)) s = 0.f;
    }
}

// ---------------- inter-chunk contribution via MFMA: y += dec * (C @ Sprev) ----------------
__global__ __launch_bounds__(256) void k_inter(const float* __restrict__ Cm,
        const float* __restrict__ Sprev, const float* __restrict__ dec,
        float* __restrict__ ybuf){
    __shared__ short Cs[64][72];   // A: rows i, k=n
    __shared__ short Ss[64][72];   // B: rows d, k=n (transposed Sprev)
    int c=blockIdx.x, b=blockIdx.y, d0=blockIdx.z*64;
    size_t rowbase=(size_t)b*L_+(size_t)c*64;
    size_t cb=(size_t)c*4+b;
    int tid=threadIdx.x, w=tid>>6, lane=tid&63;
    int wr=w>>1, wc=w&1, quad=lane>>4, r16=lane&15;
    {
        int row=tid&63, cg=(tid>>6)*16;
        const float* cp=Cm+(rowbase+row)*64+cg;
        float4 c0=*(const float4*)cp, c1=*(const float4*)(cp+4),
               c2=*(const float4*)(cp+8), c3=*(const float4*)(cp+12);
        *(short8*)&Cs[row][cg]   = cvt8(c0,c1);
        *(short8*)&Cs[row][cg+8] = cvt8(c2,c3);
        int n=tid>>2, dg=(tid&3)*16;
        const float* sp=Sprev+(cb*64+n)*512+d0+dg;
        float4 v0=*(const float4*)sp, v1=*(const float4*)(sp+4),
               v2=*(const float4*)(sp+8), v3=*(const float4*)(sp+12);
        Ss[dg+ 0][n]=f2bs(v0.x); Ss[dg+ 1][n]=f2bs(v0.y); Ss[dg+ 2][n]=f2bs(v0.z); Ss[dg+ 3][n]=f2bs(v0.w);
        Ss[dg+ 4][n]=f2bs(v1.x); Ss[dg+ 5][n]=f2bs(v1.y); Ss[dg+ 6][n]=f2bs(v1.z); Ss[dg+ 7][n]=f2bs(v1.w);
        Ss[dg+ 8][n]=f2bs(v2.x); Ss[dg+ 9][n]=f2bs(v2.y); Ss[dg+10][n]=f2bs(v2.z); Ss[dg+11][n]=f2bs(v2.w);
        Ss[dg+12][n]=f2bs(v3.x); Ss[dg+13][n]=f2bs(v3.y); Ss[dg+14][n]=f2bs(v3.z); Ss[dg+15][n]=f2bs(v3.w);
    }
    __syncthreads();
    floatx4 acc[2][2];
    #pragma unroll
    for (int i=0;i<2;i++)
        #pragma unroll
        for (int j=0;j<2;j++)
            #pragma unroll
            for (int e=0;e<4;e++) acc[i][j][e]=0.f;
    #pragma unroll
    for (int ks=0;ks<2;ks++){
        short8 af[2], bv[2];
        #pragma unroll
        for (int i=0;i<2;i++) af[i]=*(short8*)&Cs[wr*32+i*16+r16][ks*32+quad*8];
        #pragma unroll
        for (int j=0;j<2;j++) bv[j]=*(short8*)&Ss[wc*32+j*16+r16][ks*32+quad*8];
        #pragma unroll
        for (int i=0;i<2;i++)
            #pragma unroll
            for (int j=0;j<2;j++)
                acc[i][j]=__builtin_amdgcn_mfma_f32_16x16x32_bf16(af[i],bv[j],acc[i][j],0,0,0);
    }
    #pragma unroll
    for (int i=0;i<2;i++)
    #pragma unroll
    for (int j=0;j<2;j++)
    #pragma unroll
    for (int reg=0;reg<4;reg++){
        int gi = wr*32+i*16+quad*4+reg;
        int gd = d0+wc*32+j*16+r16;
        size_t off=(rowbase+gi)*512+gd;
        ybuf[off]=fmaf(dec[off],acc[i][j][reg],ybuf[off]);
    }
}

// ---------------- +D_skip*xbar, rmsnorm(d=512), *silu(z) -> u (bf16) ----------------
__global__ __launch_bounds__(256) void k_outnorm(const float* __restrict__ y,
        const float* __restrict__ xbar, const float* __restrict__ Dskip,
        const float* __restrict__ g, const bf16* __restrict__ siluz,
        bf16* __restrict__ u){
    int wave = threadIdx.x >> 6, lane = threadIdx.x & 63;
    size_t row = (size_t)blockIdx.x*4 + wave;
    float v[8]; float ss = 0.f;
    #pragma unroll
    for (int j=0;j<8;j++){
        int d = j*64 + lane;
        float yv = y[row*512 + d];
        if (!isfinite(yv)) yv = 0.f;
        float t = yv + Dskip[d] * xbar[row*512 + d];
        v[j] = t; ss += t*t;
    }
    #pragma unroll
    for (int m=1;m<64;m<<=1) ss += __shfl_xor(ss, m, 64);
    float r = rsqrtf(ss*(1.f/512.f) + 1e-6f);
    #pragma unroll
    for (int j=0;j<8;j++){
        int d = j*64 + lane;
        u[row*512 + d] = f2b(v[j] * r * g[d] * b2f(siluz[row*512 + d]));
    }
}

extern "C" void kernel_launch(void* const* d_in, const int* in_sizes, int n_in,
                              void* d_out, int out_size, void* d_ws, size_t ws_size,
                              hipStream_t stream){
    const float* x       = (const float*)d_in[0];
    const float* A_log   = (const float*)d_in[1];
    const float* dt_bias = (const float*)d_in[2];
    const float* D_skip  = (const float*)d_in[3];
    const float* W_xproj = (const float*)d_in[4];
    const float* b_xproj = (const float*)d_in[5];
    const float* W_B     = (const float*)d_in[6];
    const float* W_C     = (const float*)d_in[7];
    const float* W_dt    = (const float*)d_in[8];
    const float* g_B     = (const float*)d_in[9];
    const float* g_C     = (const float*)d_in[10];
    const float* g_out   = (const float*)d_in[11];
    const float* W_out   = (const float*)d_in[12];
    const float* b_out   = (const float*)d_in[13];
    float* out = (float*)d_out;

    char* wp = (char*)d_ws;
    auto alloc = [&](size_t bytes)->char*{ char* p = wp; wp += (bytes + 255) & ~(size_t)255; return p; };
    float* xbar  = (float*)alloc((size_t)M_*512*4);
    bf16*  xbarh = (bf16*) alloc((size_t)M_*512*2);
    bf16*  siluz = (bf16*) alloc((size_t)M_*512*2);
    float* la    = (float*)alloc((size_t)M_*512*4);        // becomes dec after k_pass1
    float* Bm    = (float*)alloc((size_t)M_*64*4);
    float* Cm    = (float*)alloc((size_t)M_*64*4);
    float* local = (float*)alloc((size_t)256*64*512*4);    // (c,b,n,d); Sprev after k_scan
    float* atot  = (float*)alloc((size_t)256*512*4);
    float* ybuf  = (float*)alloc((size_t)M_*512*4);
    bf16*  u     = (bf16*) alloc((size_t)M_*512*2);
    bf16*  WtX   = (bf16*) alloc((size_t)1024*512*2);
    bf16*  WtD   = (bf16*) alloc((size_t)512*512*2);
    bf16*  WtO   = (bf16*) alloc((size_t)512*512*2);
    bf16*  WtB   = (bf16*) alloc((size_t)64*512*2);
    bf16*  WtC   = (bf16*) alloc((size_t)64*512*2);

    dim3 tb(32,32);
    k_transpose<<<dim3(32,16), tb, 0, stream>>>(W_xproj, WtX, 512, 1024);
    k_transpose<<<dim3(16,16), tb, 0, stream>>>(W_dt,   WtD, 512, 512);
    k_transpose<<<dim3(16,16), tb, 0, stream>>>(W_out,  WtO, 512, 512);
    k_transpose<<<dim3(2,16),  tb, 0, stream>>>(W_B,    WtB, 512, 64);
    k_transpose<<<dim3(2,16),  tb, 0, stream>>>(W_C,    WtC, 512, 64);

    k_gemm128<0,true> <<<dim3(128, 8), 256, 0, stream>>>(x,     WtX, b_xproj, nullptr, xbar, xbarh, siluz);
    k_bcproj          <<<dim3(256, 2), 256, 0, stream>>>(xbarh, WtB, WtC, g_B, g_C, Bm, Cm);
    k_gemm128<1,false><<<dim3(128, 4), 256, 0, stream>>>(xbarh, WtD, dt_bias, A_log, la, nullptr, nullptr);
    k_pass1           <<<dim3(64, 4),  512, 0, stream>>>(la, xbar, Bm, Cm, ybuf, local, atot);
    k_scan            <<<512,          256, 0, stream>>>(local, atot);
    k_inter           <<<dim3(64,4,8), 256, 0, stream>>>(Cm, local, la, ybuf);
    k_outnorm         <<<M_/4,         256, 0, stream>>>(ybuf, xbar, D_skip, g_out, siluz, u);
    k_gemm128<2,false><<<dim3(128, 4), 256, 0, stream>>>(u,     WtO, b_out, nullptr, out, nullptr, nullptr);
}

// Round 4
// 372.370 us; speedup vs baseline: 1.0841x; 1.0841x over previous
//
#include <hip/hip_runtime.h>
#include <hip/hip_bf16.h>
#include <math.h>

typedef __hip_bfloat16 bf16;
typedef __attribute__((ext_vector_type(8))) short short8;
typedef __attribute__((ext_vector_type(4))) float floatx4;

#define B_ 4
#define L_ 4096
#define D_ 512
#define M_ (B_*L_)   // 16384 rows

__device__ __forceinline__ float b2f(bf16 v){ return __bfloat162float(v); }
__device__ __forceinline__ bf16  f2b(float v){ return __float2bfloat16(v); }
__device__ __forceinline__ short f2bs(float v){ bf16 h = __float2bfloat16(v); short s; __builtin_memcpy(&s,&h,2); return s; }

#define GLD16(gp, lp) __builtin_amdgcn_global_load_lds( \
    (const __attribute__((address_space(1))) void*)(gp), \
    (__attribute__((address_space(3))) void*)(lp), 16, 0, 0)

// ---------------- weight transpose+downcast (K,N) f32 -> (N,K) bf16 ----------------
__global__ __launch_bounds__(1024) void k_transpose(const float* __restrict__ src,
                                                    bf16* __restrict__ dst, int K, int N){
    __shared__ float tile[32][33];
    int n0 = blockIdx.x*32, k0 = blockIdx.y*32;
    int tx = threadIdx.x, ty = threadIdx.y;
    tile[ty][tx] = src[(size_t)(k0+ty)*N + n0+tx];
    __syncthreads();
    ((short*)dst)[(size_t)(n0+ty)*K + k0+tx] = f2bs(tile[tx][ty]);
}

// ---------------- f32 -> bf16 bulk convert ----------------
__global__ __launch_bounds__(256) void k_cvt(const float* __restrict__ src,
                                             bf16* __restrict__ dst){
    size_t i = ((size_t)blockIdx.x*256 + threadIdx.x)*4;
    float4 v = *(const float4*)(src + i);
    short4 s; s.x=f2bs(v.x); s.y=f2bs(v.y); s.z=f2bs(v.z); s.w=f2bs(v.w);
    *(short4*)((short*)dst + i) = s;
}

// ---------------- 128x128 MFMA GEMM (m97 pattern), K=512, fused epilogues ----------------
// A (M,K) bf16 row-major; Wt (N,K) bf16 row-major. 256 thr = 4 waves 2x2, wave=64x64.
// Staging via global_load_lds width 16 into UNPADDED [128][32] (fragment reads cover a
// contiguous 1KB per wave -> conflict-free).
// EPI 0: xproj  (bias; gc<512: xbar f32 + xbarh bf16 ; gc>=512: silu->siluz)
// EPI 1: dt     (bias, softplus/clip, *A -> la)
// EPI 2: out    (bias -> f32 out)
template<int EPI>
__global__ __launch_bounds__(256) void k_gemm(const bf16* __restrict__ Ap,
        const bf16* __restrict__ Wt, const float* __restrict__ bias,
        const float* __restrict__ aux,
        float* __restrict__ o1, bf16* __restrict__ o2, bf16* __restrict__ o3){
    __shared__ short As[128*32];
    __shared__ short Bs[128*32];
    const int K = 512;
    int m0 = blockIdx.x*128, n0 = blockIdx.y*128;
    int tid=threadIdx.x, w=tid>>6, lane=tid&63;
    int wr=w>>1, wc=w&1, quad=lane>>4, r16=lane&15;
    floatx4 acc[4][4];
    #pragma unroll
    for (int i=0;i<4;i++)
        #pragma unroll
        for (int j=0;j<4;j++)
            #pragma unroll
            for (int e=0;e<4;e++) acc[i][j][e]=0.f;

    // chunk ids: c covers (row=c>>2, 16B group c&3)
    int c0 = tid, c1 = tid + 256;
    const short* Ab = (const short*)Ap + (size_t)m0*K;
    const short* Wb = (const short*)Wt + (size_t)n0*K;
    int r0 = c0>>2, g0 = (c0&3)*8;
    int r1 = c1>>2, g1 = (c1&3)*8;

    for (int k0=0;k0<K;k0+=32){
        GLD16(Ab + (size_t)r0*K + k0 + g0, &As[c0*8]);
        GLD16(Ab + (size_t)r1*K + k0 + g1, &As[c1*8]);
        GLD16(Wb + (size_t)r0*K + k0 + g0, &Bs[c0*8]);
        GLD16(Wb + (size_t)r1*K + k0 + g1, &Bs[c1*8]);
        __syncthreads();
        short8 af[4], bv[4];
        #pragma unroll
        for (int i=0;i<4;i++) af[i] = *(short8*)&As[(wr*64+i*16+r16)*32 + quad*8];
        #pragma unroll
        for (int j=0;j<4;j++) bv[j] = *(short8*)&Bs[(wc*64+j*16+r16)*32 + quad*8];
        #pragma unroll
        for (int i=0;i<4;i++)
            #pragma unroll
            for (int j=0;j<4;j++)
                acc[i][j] = __builtin_amdgcn_mfma_f32_16x16x32_bf16(af[i], bv[j], acc[i][j], 0,0,0);
        __syncthreads();
    }
    #pragma unroll
    for (int i=0;i<4;i++)
    #pragma unroll
    for (int j=0;j<4;j++)
    #pragma unroll
    for (int reg=0;reg<4;reg++){
        int gr = m0 + wr*64 + i*16 + quad*4 + reg;
        int gc = n0 + wc*64 + j*16 + r16;
        float v = acc[i][j][reg] + bias[gc];
        if (EPI==0){
            if (gc < 512){
                o1[(size_t)gr*512 + gc] = v;
                o2[(size_t)gr*512 + gc] = f2b(v);
            } else {
                o3[(size_t)gr*512 + (gc-512)] = f2b(v / (1.f + __expf(-v)));
            }
        } else if (EPI==1){
            float sp = (v > 15.f) ? v : log1pf(__expf(v));
            float dt = fminf(fmaxf(sp, 1e-4f), 5.f);
            float Ad = -__expf(fminf(fmaxf(aux[gc], -20.f), 2.f));
            o1[(size_t)gr*512 + gc] = fminf(fmaxf(dt*Ad, -18.420680743952367f), 0.f);
        } else {
            o1[(size_t)gr*512 + gc] = v;
        }
    }
}

// ---------------- 64x64 tile core (bf16 A) for the skinny B/C proj ----------------
__device__ __forceinline__ void gemm_tile_64x64(const bf16* __restrict__ Aptr,
                                                const bf16* __restrict__ Wt,
                                                int K, int m0, int n0,
                                                short (*As)[32], short (*Ns)[32],
                                                floatx4 acc[2][2]){
    int tid  = threadIdx.x;
    int w    = tid >> 6, lane = tid & 63;
    int wr   = w >> 1,  wc   = w & 1;
    int quad = lane >> 4, r16 = lane & 15;
    #pragma unroll
    for (int i=0;i<2;i++)
        #pragma unroll
        for (int j=0;j<2;j++)
            #pragma unroll
            for (int e=0;e<4;e++) acc[i][j][e] = 0.f;
    int lrow = tid >> 2, lkg = (tid & 3) * 8;
    for (int k0 = 0; k0 < K; k0 += 32){
        *(short8*)&As[lrow][lkg] = *(const short8*)((const short*)Aptr + (size_t)(m0+lrow)*K + k0 + lkg);
        *(short8*)&Ns[lrow][lkg] = *(const short8*)((const short*)Wt   + (size_t)(n0+lrow)*K + k0 + lkg);
        __syncthreads();
        short8 af[2], bfr[2];
        #pragma unroll
        for (int t=0;t<2;t++) af[t]  = *(short8*)&As[wr*32 + t*16 + r16][quad*8];
        #pragma unroll
        for (int t=0;t<2;t++) bfr[t] = *(short8*)&Ns[wc*32 + t*16 + r16][quad*8];
        #pragma unroll
        for (int i=0;i<2;i++)
            #pragma unroll
            for (int j=0;j<2;j++)
                acc[i][j] = __builtin_amdgcn_mfma_f32_16x16x32_bf16(af[i], bfr[j], acc[i][j], 0,0,0);
        __syncthreads();
    }
}

// ---------------- B/C projection GEMM + rmsnorm over n=64 ----------------
__global__ __launch_bounds__(256) void k_bcproj(const bf16* __restrict__ xbarh,
        const bf16* __restrict__ WtB, const bf16* __restrict__ WtC,
        const float* __restrict__ gB, const float* __restrict__ gC,
        float* __restrict__ Bm, float* __restrict__ Cm){
    __shared__ short As[64][32], Ns[64][32];
    __shared__ float Ls[64][64];
    __shared__ float rfac[64];
    const bf16* Wt = blockIdx.y ? WtC : WtB;
    const float* g = blockIdx.y ? gC  : gB;
    float* outp    = blockIdx.y ? Cm  : Bm;
    floatx4 acc[2][2];
    int m0 = blockIdx.x*64;
    gemm_tile_64x64(xbarh, Wt, 512, m0, 0, As, Ns, acc);
    int tid=threadIdx.x, w=tid>>6, lane=tid&63, wr=w>>1, wc=w&1, quad=lane>>4, r16=lane&15;
    #pragma unroll
    for (int i=0;i<2;i++)
    #pragma unroll
    for (int j=0;j<2;j++)
    #pragma unroll
    for (int reg=0;reg<4;reg++)
        Ls[wr*32+i*16+quad*4+reg][wc*32+j*16+r16] = acc[i][j][reg];
    __syncthreads();
    if (tid < 64){
        float ss = 0.f;
        #pragma unroll
        for (int cc=0;cc<64;cc++){ float t = Ls[tid][cc]; ss += t*t; }
        rfac[tid] = rsqrtf(ss*(1.f/64.f) + 1e-6f);
    }
    __syncthreads();
    #pragma unroll
    for (int it=0; it<16; it++){
        int idx = it*256 + tid;
        int r = idx >> 6, cc = idx & 63;
        outp[(size_t)(m0+r)*64 + cc] = Ls[r][cc] * rfac[r] * g[cc];
    }
}

// ---------------- pass1: chunk-local final state only ----------------
// grid (64 chunks, 4 batch, 2 d-halves), 256 thr. B chunk staged in LDS (16KB).
__global__ __launch_bounds__(256) void k_pass1(const float* __restrict__ la,
        const float* __restrict__ xbar, const float* __restrict__ Bm,
        float* __restrict__ local, float* __restrict__ atot){
    __shared__ float Bs[64*64];
    int c=blockIdx.x, b=blockIdx.y, d=blockIdx.z*256+threadIdx.x;
    size_t rowbase=(size_t)b*L_+(size_t)c*64;
    size_t cb=(size_t)c*4+b;
    {   // chunk slab of Bm is 4096 contiguous floats
        const float4* src=(const float4*)(Bm + rowbase*64);
        float4* dst=(float4*)Bs;
        #pragma unroll
        for (int k=0;k<4;k++) dst[k*256+threadIdx.x]=src[k*256+threadIdx.x];
    }
    __syncthreads();
    float4 st[16];
    #pragma unroll
    for (int k=0;k<16;k++) st[k]=make_float4(0.f,0.f,0.f,0.f);
    float cs=0.f;
    size_t off0=rowbase*512+d;
    float la_n=la[off0], x_n=xbar[off0];
    #pragma unroll 2
    for (int i=0;i<64;i++){
        float lai=la_n, xi=x_n;
        if (i<63){ la_n=la[off0+(i+1)*512]; x_n=xbar[off0+(i+1)*512]; }
        float ai=__expf(lai);
        cs += lai;
        const float* Br=Bs+i*64;
        #pragma unroll
        for (int k=0;k<16;k++){
            float4 bv=*(const float4*)(Br+k*4);
            float4 s=st[k];
            s.x=fmaf(ai,s.x,bv.x*xi); s.y=fmaf(ai,s.y,bv.y*xi);
            s.z=fmaf(ai,s.z,bv.z*xi); s.w=fmaf(ai,s.w,bv.w*xi);
            st[k]=s;
        }
    }
    #pragma unroll
    for (int k=0;k<16;k++){
        size_t ob=(cb*64 + k*4)*512 + d;
        local[ob]      = st[k].x;
        local[ob+512]  = st[k].y;
        local[ob+1024] = st[k].z;
        local[ob+1536] = st[k].w;
    }
    atot[cb*512+d]=__expf(cs);
}

// ---------------- sequential inter-chunk scan (in place) ----------------
__global__ __launch_bounds__(256) void k_scan(float* __restrict__ local,
        const float* __restrict__ atot){
    int idx = blockIdx.x*256 + threadIdx.x;      // over b*n*d = 131072
    int d = idx & 511, n = (idx >> 9) & 63, b = idx >> 15;
    float s = 0.f;
    for (int c=0;c<64;c++){
        size_t cb = (size_t)c*4 + b;
        size_t off = (cb*64 + n)*512 + d;
        float v = local[off];
        local[off] = s;                           // state entering chunk c
        s = s * atot[cb*512 + d] + v;
        if (!isfinite(s)) s = 0.f;
    }
}

// ---------------- pass2: full recurrence seeded by Sprev -> y ----------------
__global__ __launch_bounds__(256) void k_pass2(const float* __restrict__ la,
        const float* __restrict__ xbar, const float* __restrict__ Bm,
        const float* __restrict__ Cm, const float* __restrict__ Sprev,
        float* __restrict__ ybuf){
    __shared__ float Bs[64*64];
    __shared__ float Cs[64*64];
    int c=blockIdx.x, b=blockIdx.y, d=blockIdx.z*256+threadIdx.x;
    size_t rowbase=(size_t)b*L_+(size_t)c*64;
    size_t cb=(size_t)c*4+b;
    {
        const float4* sb=(const float4*)(Bm + rowbase*64);
        const float4* sc=(const float4*)(Cm + rowbase*64);
        float4* db=(float4*)Bs; float4* dc=(float4*)Cs;
        #pragma unroll
        for (int k=0;k<4;k++){
            db[k*256+threadIdx.x]=sb[k*256+threadIdx.x];
            dc[k*256+threadIdx.x]=sc[k*256+threadIdx.x];
        }
    }
    float4 st[16];
    #pragma unroll
    for (int k=0;k<16;k++){
        size_t ib=(cb*64 + k*4)*512 + d;
        st[k].x=Sprev[ib]; st[k].y=Sprev[ib+512];
        st[k].z=Sprev[ib+1024]; st[k].w=Sprev[ib+1536];
    }
    __syncthreads();
    size_t off0=rowbase*512+d;
    float la_n=la[off0], x_n=xbar[off0];
    #pragma unroll 2
    for (int i=0;i<64;i++){
        float lai=la_n, xi=x_n;
        if (i<63){ la_n=la[off0+(i+1)*512]; x_n=xbar[off0+(i+1)*512]; }
        float ai=__expf(lai);
        const float* Br=Bs+i*64;
        const float* Cr=Cs+i*64;
        float4 yv=make_float4(0.f,0.f,0.f,0.f);
        #pragma unroll
        for (int k=0;k<16;k++){
            float4 bv=*(const float4*)(Br+k*4);
            float4 cv=*(const float4*)(Cr+k*4);
            float4 s=st[k];
            s.x=fmaf(ai,s.x,bv.x*xi); s.y=fmaf(ai,s.y,bv.y*xi);
            s.z=fmaf(ai,s.z,bv.z*xi); s.w=fmaf(ai,s.w,bv.w*xi);
            st[k]=s;
            yv.x=fmaf(cv.x,s.x,yv.x); yv.y=fmaf(cv.y,s.y,yv.y);
            yv.z=fmaf(cv.z,s.z,yv.z); yv.w=fmaf(cv.w,s.w,yv.w);
        }
        float yo=(yv.x+yv.y)+(yv.z+yv.w);
        if (!isfinite(yo)) yo=0.f;
        ybuf[off0+i*512]=yo;
    }
}

// ---------------- +D_skip*xbar, rmsnorm(d=512), *silu(z) -> u (bf16) ----------------
__global__ __launch_bounds__(256) void k_outnorm(const float* __restrict__ y,
        const float* __restrict__ xbar, const float* __restrict__ Dskip,
        const float* __restrict__ g, const bf16* __restrict__ siluz,
        bf16* __restrict__ u){
    int wave = threadIdx.x >> 6, lane = threadIdx.x & 63;
    size_t row = (size_t)blockIdx.x*4 + wave;
    float v[8]; float ss = 0.f;
    #pragma unroll
    for (int j=0;j<8;j++){
        int d = j*64 + lane;
        float t = y[row*512 + d] + Dskip[d] * xbar[row*512 + d];
        v[j] = t; ss += t*t;
    }
    #pragma unroll
    for (int m=1;m<64;m<<=1) ss += __shfl_xor(ss, m, 64);
    float r = rsqrtf(ss*(1.f/512.f) + 1e-6f);
    #pragma unroll
    for (int j=0;j<8;j++){
        int d = j*64 + lane;
        u[row*512 + d] = f2b(v[j] * r * g[d] * b2f(siluz[row*512 + d]));
    }
}

extern "C" void kernel_launch(void* const* d_in, const int* in_sizes, int n_in,
                              void* d_out, int out_size, void* d_ws, size_t ws_size,
                              hipStream_t stream){
    const float* x       = (const float*)d_in[0];
    const float* A_log   = (const float*)d_in[1];
    const float* dt_bias = (const float*)d_in[2];
    const float* D_skip  = (const float*)d_in[3];
    const float* W_xproj = (const float*)d_in[4];
    const float* b_xproj = (const float*)d_in[5];
    const float* W_B     = (const float*)d_in[6];
    const float* W_C     = (const float*)d_in[7];
    const float* W_dt    = (const float*)d_in[8];
    const float* g_B     = (const float*)d_in[9];
    const float* g_C     = (const float*)d_in[10];
    const float* g_out   = (const float*)d_in[11];
    const float* W_out   = (const float*)d_in[12];
    const float* b_out   = (const float*)d_in[13];
    float* out = (float*)d_out;

    char* wp = (char*)d_ws;
    auto alloc = [&](size_t bytes)->char*{ char* p = wp; wp += (bytes + 255) & ~(size_t)255; return p; };
    float* xbar  = (float*)alloc((size_t)M_*512*4);
    bf16*  xh    = (bf16*) alloc((size_t)M_*512*2);
    bf16*  xbarh = (bf16*) alloc((size_t)M_*512*2);
    bf16*  siluz = (bf16*) alloc((size_t)M_*512*2);
    float* la    = (float*)alloc((size_t)M_*512*4);
    float* Bm    = (float*)alloc((size_t)M_*64*4);
    float* Cm    = (float*)alloc((size_t)M_*64*4);
    float* local = (float*)alloc((size_t)256*64*512*4);    // (c,b,n,d); Sprev after k_scan
    float* atot  = (float*)alloc((size_t)256*512*4);
    float* ybuf  = (float*)alloc((size_t)M_*512*4);
    bf16*  u     = (bf16*) alloc((size_t)M_*512*2);
    bf16*  WtX   = (bf16*) alloc((size_t)1024*512*2);
    bf16*  WtD   = (bf16*) alloc((size_t)512*512*2);
    bf16*  WtO   = (bf16*) alloc((size_t)512*512*2);
    bf16*  WtB   = (bf16*) alloc((size_t)64*512*2);
    bf16*  WtC   = (bf16*) alloc((size_t)64*512*2);

    dim3 tb(32,32);
    k_transpose<<<dim3(32,16), tb, 0, stream>>>(W_xproj, WtX, 512, 1024);
    k_transpose<<<dim3(16,16), tb, 0, stream>>>(W_dt,   WtD, 512, 512);
    k_transpose<<<dim3(16,16), tb, 0, stream>>>(W_out,  WtO, 512, 512);
    k_transpose<<<dim3(2,16),  tb, 0, stream>>>(W_B,    WtB, 512, 64);
    k_transpose<<<dim3(2,16),  tb, 0, stream>>>(W_C,    WtC, 512, 64);
    k_cvt      <<<M_*512/1024, 256, 0, stream>>>(x, xh);

    k_gemm<0> <<<dim3(128, 8), 256, 0, stream>>>(xh,    WtX, b_xproj, nullptr, xbar, xbarh, siluz);
    k_bcproj  <<<dim3(256, 2), 256, 0, stream>>>(xbarh, WtB, WtC, g_B, g_C, Bm, Cm);
    k_gemm<1> <<<dim3(128, 4), 256, 0, stream>>>(xbarh, WtD, dt_bias, A_log, la, nullptr, nullptr);
    k_pass1   <<<dim3(64,4,2), 256, 0, stream>>>(la, xbar, Bm, local, atot);
    k_scan    <<<512,          256, 0, stream>>>(local, atot);
    k_pass2   <<<dim3(64,4,2), 256, 0, stream>>>(la, xbar, Bm, Cm, local, ybuf);
    k_outnorm <<<M_/4,         256, 0, stream>>>(ybuf, xbar, D_skip, g_out, siluz, u);
    k_gemm<2> <<<dim3(128, 4), 256, 0, stream>>>(u,     WtO, b_out, nullptr, out, nullptr, nullptr);
}